// Round 12
// baseline (234.561 us; speedup 1.0000x reference)
//
#include <hip/hip_runtime.h>

// SoftDTW: B=16, T=1024, C=64, gamma=0.01, BIG=1e10
// out = sum_b softdtw(cost[b]) ; cost[b][i][j] = ||x[b,i]-y[b,j]||^2
//
// R12: (1) skew_cost 128x128 tile, 8x8/thread: fma-per-ds_read_b128 doubles
// (8->16), LDS pipe traffic halves (R11 bound: ~8 b128 per 64 fma ~= 40us).
// Shear/store runs per-64x64 quadrant with the byte-identical verified R11
// tail -> output layout unchanged, dtw untouched. (2) dtw half-window
// message flush/wait: producer publishes boundary in 32-col halves;
// consumer waits lower half before grp32<.,0>, upper before grp32<.,32>.
// Offset 2 -> ~1.5 windows and kills the systematic prefetch-miss race.

#define TT 1024
#define BB 16
#define CC 64
#define BIGV 1e10f
#define NB 8                  // bands
#define NPAIR 7               // band pairs per batch
#define PROWS 8192            // t-rows per plane

// ---------------------------------------------------------------------------
// Kernel 1: cost tile 128x128 -> 2-plane t-quad skewed store via LDS shear.
// cost = |x|^2 + |y|^2 + sum(-2x*y); xs staged pre-scaled by -2.
// ---------------------------------------------------------------------------
__global__ __launch_bounds__(256) void skew_cost_kernel(const float* __restrict__ x,
                                                        const float* __restrict__ y,
                                                        float* __restrict__ skew) {
    __shared__ __align__(16) float xs[128 * 68];   // stage (-2x); shear overlay
    __shared__ __align__(16) float ys[128 * 68];
    __shared__ float pnx[128 * 17], pny[128 * 17]; // norm partials
    __shared__ float xn[128], yn[128];
    const int bx2 = blockIdx.x;      // col tile (j0 = 128*bx2), 0..7
    const int by2 = blockIdx.y;      // row tile (i0 = 128*by2), 0..7
    const int bz = blockIdx.z;       // batch
    const int tid = threadIdx.x;

    const float4* xg = (const float4*)(x + ((size_t)bz * TT + by2 * 128) * CC);
    const float4* yg = (const float4*)(y + ((size_t)bz * TT + bx2 * 128) * CC);
#pragma unroll
    for (int t = 0; t < 8; ++t) {
        int idx = t * 256 + tid;     // 0..2047
        int r = idx >> 4, f = idx & 15;
        float4 v = xg[idx];
        float4 vs = make_float4(-2.f * v.x, -2.f * v.y, -2.f * v.z, -2.f * v.w);
        *(float4*)&xs[r * 68 + f * 4] = vs;
        pnx[r * 17 + f] = v.x * v.x + v.y * v.y + v.z * v.z + v.w * v.w;
        float4 u = yg[idx];
        *(float4*)&ys[r * 68 + f * 4] = u;
        pny[r * 17 + f] = u.x * u.x + u.y * u.y + u.z * u.z + u.w * u.w;
    }
    __syncthreads();

    if (tid < 128) {                 // conflict-free partial reduce (17-stride)
        float sx = 0.f, sy = 0.f;
#pragma unroll
        for (int k = 0; k < 16; ++k) {
            sx += pnx[tid * 17 + k];
            sy += pny[tid * 17 + k];
        }
        xn[tid] = sx; yn[tid] = sy;
    }

    // x rows {tr+16a} (broadcast reads), y rows {tc+16b} (<=2-way reads).
    const int tr = tid >> 4, tc = tid & 15;
    float acc[8][8] = {};            // accumulates -2 * x.y
#pragma unroll 4
    for (int k4 = 0; k4 < 16; ++k4) {
        float4 xa4[8], yb4[8];
#pragma unroll
        for (int a = 0; a < 8; ++a)
            xa4[a] = *(const float4*)&xs[(tr + 16 * a) * 68 + 4 * k4];
#pragma unroll
        for (int b = 0; b < 8; ++b)
            yb4[b] = *(const float4*)&ys[(tc + 16 * b) * 68 + 4 * k4];
#pragma unroll
        for (int a = 0; a < 8; ++a)
#pragma unroll
            for (int b = 0; b < 8; ++b) {
                acc[a][b] = fmaf(xa4[a].x, yb4[b].x, acc[a][b]);
                acc[a][b] = fmaf(xa4[a].y, yb4[b].y, acc[a][b]);
                acc[a][b] = fmaf(xa4[a].z, yb4[b].z, acc[a][b]);
                acc[a][b] = fmaf(xa4[a].w, yb4[b].w, acc[a][b]);
            }
    }
    __syncthreads();                 // norms visible; stage reads done (overlay ok)

    float xnr[8], ynr[8];
#pragma unroll
    for (int a = 0; a < 8; ++a) { xnr[a] = xn[tr + 16 * a]; ynr[a] = yn[tc + 16 * a]; }

    // per-64x64 quadrant: verified R11 shear + quad-layout store.
    float* sh = xs;                  // 2*3135 = 6270 <= 8704 (xs region)
#pragma unroll 1
    for (int Q = 0; Q < 4; ++Q) {
        const int A = Q >> 1, B = Q & 1;
        // shear: sh[r][t_rel][l_rel]; il = tr+16a' (a'=0..3), jl = tc+16b'.
#pragma unroll
        for (int a = 0; a < 4; ++a)
#pragma unroll
            for (int b = 0; b < 4; ++b) {
                int lr = (tr >> 1) + 8 * a;
                int t_rel = (tc + 16 * b) + lr;
                sh[(tr & 1) * 3135 + t_rel * 33 + lr] =
                    acc[4 * A + a][4 * B + b] + xnr[4 * A + a] + ynr[4 * B + b];
            }
        __syncthreads();

        const int by = 2 * by2 + A;          // 0..15
        const int bx = 2 * bx2 + B;          // 0..15
        const int wv = tid >> 6;
        if (wv < 2) {
            const int r = wv;
            const int lane = tid & 63;
            const int l_rel = lane & 31;
            const int half = lane >> 5;
            const int p = by >> 1;
            const int l0 = (by & 1) * 32;
            const int tb = p * 1024 + bx * 64 + l0;      // multiple of 4
            const float* shr = sh + r * 3135 + l_rel;
            float* sb = skew + (size_t)bz * 2 * PROWS * 64
                      + (size_t)r * PROWS * 64 + (size_t)(l0 + l_rel) * 4;
            const int base_t = l_rel + 32 * half;
            const int m = l_rel & 3;
            const int lead = (4 - m) & 3;
#pragma unroll
            for (int e = 0; e < 3; ++e) {
                if (e < lead) {
                    int t_rel = base_t + e;
                    int t = (tb + t_rel) & (PROWS - 1);
                    sb[(size_t)(t >> 2) * 256 + (t & 3)] = shr[t_rel * 33];
                }
            }
            const int nq = (m == 0) ? 8 : 7;
#pragma unroll
            for (int s = 0; s < 8; ++s) {
                if (s < nq) {
                    int t_rel = base_t + lead + 4 * s;
                    float4 v = make_float4(shr[t_rel * 33], shr[(t_rel + 1) * 33],
                                           shr[(t_rel + 2) * 33], shr[(t_rel + 3) * 33]);
                    int t = (tb + t_rel) & (PROWS - 1);
                    *(float4*)&sb[(size_t)(t >> 2) * 256] = v;
                }
            }
            const int tail = (32 - lead) & 3;
#pragma unroll
            for (int e = 0; e < 3; ++e) {
                if (e < tail) {
                    int t_rel = base_t + 32 - tail + e;
                    int t = (tb + t_rel) & (PROWS - 1);
                    sb[(size_t)(t >> 2) * 256 + (t & 3)] = shr[t_rel * 33];
                }
            }
        }
        __syncthreads();             // store done before next quadrant's shear
    }
}

// lane l gets lane l-1's `v`; lane 0 gets `lane0val` (via dpp old operand).
__device__ __forceinline__ float shift_up1(float v, float lane0val) {
    int r = __builtin_amdgcn_update_dpp(__float_as_int(lane0val),
                                        __float_as_int(v),
                                        0x138 /*WAVE_SHR1*/, 0xF, 0xF, false);
    return __int_as_float(r);
}

// 32 DP steps x 2 rows/lane. kw = window-local step (KOFS..KOFS+31).
// PHASE: 0 = fill (l<=kw), 1 = interior, 2 = drain KOFS=0 (l>=kw+1),
// 3 = drain KOFS=32 (l>=kw+1, skip kw==63).
template <int PHASE, int KOFS>
__device__ __forceinline__ void grp32(float& curA, float& curB, float& diagA,
                                      const float (&q)[64],
                                      const float* cb, float* pA, float* pB,
                                      int l) {
#pragma unroll
    for (int g = 0; g < 8; ++g) {
        float4 b4;
        if (PHASE <= 1) b4 = *(const float4*)(cb + KOFS + 4 * g);
        else            b4 = make_float4(BIGV, BIGV, BIGV, BIGV);
        const float* bv = (const float*)&b4;
#pragma unroll
        for (int kk = 0; kk < 4; ++kk) {
            const int kw = KOFS + 4 * g + kk;
            if (!(PHASE == 3 && kw == 63)) {
                float up = shift_up1(curB, bv[kk]);         // R[iA-1][j]
                float nA = q[4 * g + kk] +
                           fminf(fminf(up, curA), diagA);   // row A
                float nB = q[32 + 4 * g + kk] +
                           fminf(fminf(nA, curB), curA);    // row B (diag=curA)
                if (PHASE == 0) {
                    bool act = (l <= kw);
                    curA = act ? nA : curA; curB = act ? nB : curB;
                } else if (PHASE >= 2) {
                    bool act = (l >= kw + 1);
                    curA = act ? nA : curA; curB = act ? nB : curB;
                } else {
                    curA = nA; curB = nB;
                }
                diagA = up;                                 // SSA rename
                if (kw < 63) pA[kw + 1] = curB;             // ring/dump
                else         pB[0] = curB;
            }
        }
    }
}

// ---------------------------------------------------------------------------
// Kernel 2: systolic DP, 1 wave per (batch, band-of-128-rows). 128 blocks.
// Lane l owns rows 128p+2l+1 (A) and 128p+2l+2 (B). 17 windows of 64 cols.
// Half-window tagged-message handoff.
// ---------------------------------------------------------------------------
__global__ __launch_bounds__(64) void dtw_sys8(const float* __restrict__ skew,
                                               unsigned long long* __restrict__ bndmsg,
                                               float* __restrict__ out) {
    __shared__ float pubring[128];
    __shared__ float dumpL[192];
    __shared__ float bndbuf[64];
    const int bid = blockIdx.x;
    const int b = bid & 15;            // batch; XCD = bid%8 = b%8 for all p
    const int p = bid >> 4;            // band 0..7
    const int l = threadIdx.x;

    const float4* B4 = (const float4*)skew + (size_t)b * 2 * PROWS * 16 + l;
    unsigned long long* BndOut = bndmsg + ((size_t)b * NPAIR + p) * TT;
    unsigned long long* BndIn  = bndmsg + ((size_t)b * NPAIR + (p > 0 ? p - 1 : 0)) * TT;

    bndbuf[l] = BIGV;                  // stays BIG for p==0 / drain

    float curA = BIGV, curB = BIGV;
    float diagA = (p == 0 && l == 0) ? 0.0f : BIGV;

    float qA[64], qB[64];              // [0..31]=plane0, [32..63]=plane1
    auto loadg = [&](int G, float (&q)[64]) {   // 32 steps, both planes
        const int t0 = (p * 1024 + 32 * G) & (PROWS - 1);   // 32-aligned wrap
        const float4* g0 = B4 + (size_t)(t0 >> 2) * 64;
        const float4* g1 = g0 + (size_t)PROWS * 16;         // plane 1
#pragma unroll
        for (int qd = 0; qd < 8; ++qd) {
            float4 v = g0[qd * 64];
            q[4 * qd + 0] = v.x; q[4 * qd + 1] = v.y;
            q[4 * qd + 2] = v.z; q[4 * qd + 3] = v.w;
        }
#pragma unroll
        for (int qd = 0; qd < 8; ++qd) {
            float4 v = g1[qd * 64];
            q[32 + 4 * qd + 0] = v.x; q[32 + 4 * qd + 1] = v.y;
            q[32 + 4 * qd + 2] = v.z; q[32 + 4 * qd + 3] = v.w;
        }
    };
    loadg(0, qA);
    loadg(1, qB);

    unsigned long long mcur = 0;
    if (p > 0)
        mcur = __hip_atomic_load(&BndIn[l], __ATOMIC_RELAXED,
                                 __HIP_MEMORY_SCOPE_AGENT);

#pragma unroll 1
    for (int V = 0; V < 17; ++V) {
        const unsigned want = (unsigned)(V + 1);
        // wait lower half of boundary block V (serves grp32<.,0>)
        if (p > 0 && V <= 15) {
            while (!__all((int)((l >= 32) | ((unsigned)(mcur >> 32) == want)))) {
                __builtin_amdgcn_s_sleep(1);
                mcur = __hip_atomic_load(&BndIn[(size_t)64 * V + l],
                                         __ATOMIC_RELAXED,
                                         __HIP_MEMORY_SCOPE_AGENT);
            }
            if (l < 32) bndbuf[l] = __uint_as_float((unsigned)mcur);
        }
        const bool is_pub = (l == 63) && (p < NB - 1);
        float* pA = (is_pub && V > 0) ? (pubring + (((V + 1) & 1) << 6))
                                      : (dumpL + l);
        float* pB = (is_pub && V < 16) ? (pubring + ((V & 1) << 6))
                                       : (dumpL + l);
        // ---- first half-window ----
        if (V == 0)      grp32<0, 0>(curA, curB, diagA, qA, bndbuf, pA, pB, l);
        else if (V < 16) grp32<1, 0>(curA, curB, diagA, qA, bndbuf, pA, pB, l);
        else             grp32<2, 0>(curA, curB, diagA, qA, bndbuf, pA, pB, l);
        // flush lower half of block V-1 (slots 0..31 complete)
        if (V >= 1 && p < NPAIR && l < 32) {
            float fv = pubring[(((V + 1) & 1) << 6) + l];
            unsigned long long msg =
                ((unsigned long long)(unsigned)V << 32) | __float_as_uint(fv);
            __hip_atomic_store(&BndOut[(size_t)64 * (V - 1) + l], msg,
                               __ATOMIC_RELAXED, __HIP_MEMORY_SCOPE_AGENT);
        }
        if (V == 0)      loadg(2, qA);
        else if (V < 16) loadg(2 * V + 2, qA);
        // wait upper half of boundary block V (serves grp32<.,32>)
        if (p > 0 && V <= 15) {
            while (!__all((int)((l < 32) | ((unsigned)(mcur >> 32) == want)))) {
                __builtin_amdgcn_s_sleep(1);
                mcur = __hip_atomic_load(&BndIn[(size_t)64 * V + l],
                                         __ATOMIC_RELAXED,
                                         __HIP_MEMORY_SCOPE_AGENT);
            }
            if (l >= 32) bndbuf[l] = __uint_as_float((unsigned)mcur);
        }
        // ---- second half-window ----
        if (V == 0)      grp32<0, 32>(curA, curB, diagA, qB, bndbuf, pA, pB, l);
        else if (V < 16) grp32<1, 32>(curA, curB, diagA, qB, bndbuf, pA, pB, l);
        else             grp32<3, 32>(curA, curB, diagA, qB, bndbuf, pA, pB, l);
        // flush upper half of block V-1 (slots 32..63 complete)
        if (V >= 1 && p < NPAIR && l >= 32) {
            float fv = pubring[(((V + 1) & 1) << 6) + l];
            unsigned long long msg =
                ((unsigned long long)(unsigned)V << 32) | __float_as_uint(fv);
            __hip_atomic_store(&BndOut[(size_t)64 * (V - 1) + l], msg,
                               __ATOMIC_RELAXED, __HIP_MEMORY_SCOPE_AGENT);
        }
        if (V == 0)       loadg(3, qB);
        else if (V < 15)  loadg(2 * V + 3, qB);
        else if (V == 15) loadg(33, qB);
        // prefetch next block's messages (reload-spin covers misses)
        if (p > 0 && V < 15)
            mcur = __hip_atomic_load(&BndIn[(size_t)64 * (V + 1) + l],
                                     __ATOMIC_RELAXED,
                                     __HIP_MEMORY_SCOPE_AGENT);
    }

    // band 7, lane 63: curB = R[1024][1024]
    if (p == NB - 1 && l == 63) atomicAdd(out, curB);
}

// ---------------------------------------------------------------------------
// Fallback (ws too small; not expected): naive fused DP.
// ---------------------------------------------------------------------------
__device__ __forceinline__ float softmin3(float a, float b, float c) {
    float m = fminf(fminf(a, b), c);
    float s = expf((m - a) * 100.0f) + expf((m - b) * 100.0f) + expf((m - c) * 100.0f);
    return m - 0.01f * logf(s);
}

__global__ __launch_bounds__(1024) void dtw_fly_kernel(const float* __restrict__ x,
                                                       const float* __restrict__ y,
                                                       float* __restrict__ out) {
    __shared__ float rbuf[3][TT + 1];
    const int b = blockIdx.x;
    const int t = threadIdx.x;

    float4 xr[16];
    const float4* xrow = (const float4*)(x + ((size_t)b * TT + t) * CC);
#pragma unroll
    for (int q = 0; q < 16; ++q) xr[q] = xrow[q];

    rbuf[0][t] = (t == 0) ? 0.0f : BIGV;
    rbuf[1][t] = BIGV;
    if (t == 0) { rbuf[0][TT] = BIGV; rbuf[1][TT] = BIGV; }
    __syncthreads();

    int p2 = 0, p1 = 1, pc = 2;
    float val = BIGV;
    for (int d = 2; d <= 2 * TT; ++d) {
        int j = d - t - 1;
        bool valid = (j >= 1) && (j <= TT);
        float cv = 0.0f;
        if (valid) {
            const float4* yr = (const float4*)(y + ((size_t)b * TT + (j - 1)) * CC);
#pragma unroll
            for (int q = 0; q < 16; ++q) {
                float4 yv = yr[q];
                float d0 = xr[q].x - yv.x, d1 = xr[q].y - yv.y;
                float d2 = xr[q].z - yv.z, d3 = xr[q].w - yv.w;
                cv += d0 * d0 + d1 * d1 + d2 * d2 + d3 * d3;
            }
        }
        float v = cv + softmin3(rbuf[p1][t], rbuf[p1][t + 1], rbuf[p2][t]);
        val = valid ? v : BIGV;
        rbuf[pc][t + 1] = val;
        if (t == 0) rbuf[pc][0] = BIGV;
        __syncthreads();
        int tmp = p2; p2 = p1; p1 = pc; pc = tmp;
    }
    if (t == TT - 1) atomicAdd(out, val);
}

extern "C" void kernel_launch(void* const* d_in, const int* in_sizes, int n_in,
                              void* d_out, int out_size, void* d_ws, size_t ws_size,
                              hipStream_t stream) {
    const float* x = (const float*)d_in[0];
    const float* y = (const float*)d_in[1];
    float* out = (float*)d_out;

    hipMemsetAsync(d_out, 0, sizeof(float) * out_size, stream);

    const size_t skew_b = (size_t)BB * 2 * PROWS * 64 * sizeof(float);       // 64 MiB
    const size_t msg_b  = (size_t)BB * NPAIR * TT * sizeof(unsigned long long); // 896 KiB

    if (ws_size >= skew_b + msg_b) {
        float* skew = (float*)d_ws;
        unsigned long long* bndmsg = (unsigned long long*)((char*)d_ws + skew_b);
        hipMemsetAsync(bndmsg, 0, msg_b, stream);   // tags := 0 (invalid)
        dim3 g1(8, 8, BB);
        skew_cost_kernel<<<g1, 256, 0, stream>>>(x, y, skew);
        dtw_sys8<<<128, 64, 0, stream>>>(skew, bndmsg, out);
    } else {
        dtw_fly_kernel<<<BB, 1024, 0, stream>>>(x, y, out);
    }
}

// Round 13
// 179.886 us; speedup vs baseline: 1.3039x; 1.3039x over previous
//
#include <hip/hip_runtime.h>
#include <hip/hip_bf16.h>

// SoftDTW: B=16, T=1024, C=64, gamma=0.01, BIG=1e10
// out = sum_b softdtw(cost[b]) ; cost[b][i][j] = ||x[b,i]-y[b,j]||^2
//
// R13: (1) dtw reverted to the R11-verified dtw_sys8 (92us; R12's
// half-window handshake regressed it to ~135us). (2) skew_cost inner
// product moved to MFMA: cost = xn + yn - 2*(x.y), cross term via
// mfma_f32_32x32x16_bf16 (K=64 = 4 chained instrs, one 32x32 quadrant
// per wave). Norms stay fp32; -2 applied in fp32 epilogue. Staging is
// bf16 ushort[64][68] (b64 frag loads, <=2-way banks). Epilogue maps
// C/D layout (col=lane&31, row=(reg&3)+8*(reg>>2)+4*(lane>>5)) into the
// same shear buffer; store tail byte-identical to R11 -> dtw input
// layout unchanged.

#define TT 1024
#define BB 16
#define CC 64
#define BIGV 1e10f
#define NB 8                  // bands
#define NPAIR 7               // band pairs per batch
#define PROWS 8192            // t-rows per plane

typedef __attribute__((ext_vector_type(8))) short short8v;
typedef __attribute__((ext_vector_type(16))) float float16v;

__device__ __forceinline__ unsigned pack_bf16(float a, float b) {
    __hip_bfloat162 h = __float22bfloat162_rn(make_float2(a, b));
    return *reinterpret_cast<unsigned*>(&h);
}

union frag_u { uint2 u[2]; short8v v; };

// ---------------------------------------------------------------------------
// Kernel 1: cost tile 64x64 -> 2-plane t-quad skewed store.
// Cross term on MFMA; norms fp32; shear + store tail as R11 (verified).
// ---------------------------------------------------------------------------
__global__ __launch_bounds__(256) void skew_cost_kernel(const float* __restrict__ x,
                                                        const float* __restrict__ y,
                                                        float* __restrict__ skew) {
    __shared__ unsigned short xs_h[64 * 68];   // bf16 x, row stride 68
    __shared__ unsigned short ys_h[64 * 68];   // bf16 y
    __shared__ float sh[6270];                 // shear buffer (2 planes)
    __shared__ float pnx[64 * 17], pny[64 * 17];
    __shared__ float xn[64], yn[64];
    const int bx = blockIdx.x;       // col tile (j0 = 64*bx)
    const int by = blockIdx.y;       // row tile (i0 = 64*by)
    const int bz = blockIdx.z;       // batch
    const int tid = threadIdx.x;

    const float4* xg = (const float4*)(x + ((size_t)bz * TT + by * 64) * CC);
    const float4* yg = (const float4*)(y + ((size_t)bz * TT + bx * 64) * CC);
#pragma unroll
    for (int t = 0; t < 4; ++t) {
        int idx = t * 256 + tid;     // 0..1023
        int r = idx >> 4, f = idx & 15;
        float4 v = xg[idx];
        *(uint2*)&xs_h[r * 68 + 4 * f] =
            make_uint2(pack_bf16(v.x, v.y), pack_bf16(v.z, v.w));
        pnx[r * 17 + f] = v.x * v.x + v.y * v.y + v.z * v.z + v.w * v.w;
        float4 u = yg[idx];
        *(uint2*)&ys_h[r * 68 + 4 * f] =
            make_uint2(pack_bf16(u.x, u.y), pack_bf16(u.z, u.w));
        pny[r * 17 + f] = u.x * u.x + u.y * u.y + u.z * u.z + u.w * u.w;
    }
    __syncthreads();

    if (tid < 128) {                 // fp32 norms (17-stride partials)
        int r = tid & 63;
        float s = 0.f;
        const float* pp = (tid < 64) ? (pnx + r * 17) : (pny + r * 17);
#pragma unroll
        for (int k = 0; k < 16; ++k) s += pp[k];
        if (tid < 64) xn[r] = s; else yn[r] = s;
    }

    // MFMA: wave w -> quadrant (A=w>>1 rows, B=w&1 cols), 32x32 over K=64.
    const int l = tid & 63;
    const int w = __builtin_amdgcn_readfirstlane(tid >> 6);
    const int half = l >> 5;         // K-half
    const int mrow = l & 31;
    const int Arow = 32 * (w >> 1) + mrow;   // x row (M index)
    const int Brow = 32 * (w & 1) + mrow;    // y row (N index)

    float16v acc;
#pragma unroll
    for (int i = 0; i < 16; ++i) acc[i] = 0.f;
#pragma unroll
    for (int c = 0; c < 4; ++c) {
        const int k0 = 16 * c + 8 * half;
        frag_u a, b;
        a.u[0] = *(const uint2*)&xs_h[Arow * 68 + k0];
        a.u[1] = *(const uint2*)&xs_h[Arow * 68 + k0 + 4];
        b.u[0] = *(const uint2*)&ys_h[Brow * 68 + k0];
        b.u[1] = *(const uint2*)&ys_h[Brow * 68 + k0 + 4];
        acc = __builtin_amdgcn_mfma_f32_32x32x16_bf16(a.v, b.v, acc, 0, 0, 0);
    }
    __syncthreads();                 // norms visible

    // epilogue: cost = xn + yn - 2*acc -> shear sh[(il&1)*3135+(jl+lr)*33+lr]
#pragma unroll
    for (int reg = 0; reg < 16; ++reg) {
        int row = (reg & 3) + 8 * (reg >> 2) + 4 * half;
        int il = 32 * (w >> 1) + row;
        int jl = 32 * (w & 1) + mrow;
        float cost = fmaf(-2.f, acc[reg], xn[il] + yn[jl]);
        int lr = il >> 1;
        sh[(il & 1) * 3135 + (jl + lr) * 33 + lr] = cost;
    }
    __syncthreads();

    // store tail (R11 verified, byte-identical output layout)
    const int wv = tid >> 6;
    if (wv < 2) {
        const int r = wv;
        const int lane = tid & 63;
        const int l_rel = lane & 31;
        const int hlf = lane >> 5;
        const int p = by >> 1;
        const int l0 = (by & 1) * 32;
        const int tb = p * 1024 + bx * 64 + l0;      // multiple of 4
        const float* shr = sh + r * 3135 + l_rel;
        float* sb = skew + (size_t)bz * 2 * PROWS * 64
                  + (size_t)r * PROWS * 64 + (size_t)(l0 + l_rel) * 4;
        const int base_t = l_rel + 32 * hlf;
        const int m = l_rel & 3;
        const int lead = (4 - m) & 3;
#pragma unroll
        for (int e = 0; e < 3; ++e) {
            if (e < lead) {
                int t_rel = base_t + e;
                int t = (tb + t_rel) & (PROWS - 1);
                sb[(size_t)(t >> 2) * 256 + (t & 3)] = shr[t_rel * 33];
            }
        }
        const int nq = (m == 0) ? 8 : 7;
#pragma unroll
        for (int s = 0; s < 8; ++s) {
            if (s < nq) {
                int t_rel = base_t + lead + 4 * s;
                float4 v = make_float4(shr[t_rel * 33], shr[(t_rel + 1) * 33],
                                       shr[(t_rel + 2) * 33], shr[(t_rel + 3) * 33]);
                int t = (tb + t_rel) & (PROWS - 1);
                *(float4*)&sb[(size_t)(t >> 2) * 256] = v;
            }
        }
        const int tail = (32 - lead) & 3;
#pragma unroll
        for (int e = 0; e < 3; ++e) {
            if (e < tail) {
                int t_rel = base_t + 32 - tail + e;
                int t = (tb + t_rel) & (PROWS - 1);
                sb[(size_t)(t >> 2) * 256 + (t & 3)] = shr[t_rel * 33];
            }
        }
    }
}

// lane l gets lane l-1's `v`; lane 0 gets `lane0val` (via dpp old operand).
__device__ __forceinline__ float shift_up1(float v, float lane0val) {
    int r = __builtin_amdgcn_update_dpp(__float_as_int(lane0val),
                                        __float_as_int(v),
                                        0x138 /*WAVE_SHR1*/, 0xF, 0xF, false);
    return __int_as_float(r);
}

// 32 DP steps x 2 rows/lane. kw = window-local step (KOFS..KOFS+31).
// PHASE: 0 = fill (l<=kw), 1 = interior, 2 = drain KOFS=0 (l>=kw+1),
// 3 = drain KOFS=32 (l>=kw+1, skip kw==63).
template <int PHASE, int KOFS>
__device__ __forceinline__ void grp32(float& curA, float& curB, float& diagA,
                                      const float (&q)[64],
                                      const float* cb, float* pA, float* pB,
                                      int l) {
#pragma unroll
    for (int g = 0; g < 8; ++g) {
        float4 b4;
        if (PHASE <= 1) b4 = *(const float4*)(cb + KOFS + 4 * g);
        else            b4 = make_float4(BIGV, BIGV, BIGV, BIGV);
        const float* bv = (const float*)&b4;
#pragma unroll
        for (int kk = 0; kk < 4; ++kk) {
            const int kw = KOFS + 4 * g + kk;
            if (!(PHASE == 3 && kw == 63)) {
                float up = shift_up1(curB, bv[kk]);         // R[iA-1][j]
                float nA = q[4 * g + kk] +
                           fminf(fminf(up, curA), diagA);   // row A
                float nB = q[32 + 4 * g + kk] +
                           fminf(fminf(nA, curB), curA);    // row B (diag=curA)
                if (PHASE == 0) {
                    bool act = (l <= kw);
                    curA = act ? nA : curA; curB = act ? nB : curB;
                } else if (PHASE >= 2) {
                    bool act = (l >= kw + 1);
                    curA = act ? nA : curA; curB = act ? nB : curB;
                } else {
                    curA = nA; curB = nB;
                }
                diagA = up;                                 // SSA rename
                if (kw < 63) pA[kw + 1] = curB;             // ring/dump
                else         pB[0] = curB;
            }
        }
    }
}

// ---------------------------------------------------------------------------
// Kernel 2 (R11-verified): systolic DP, 1 wave per (batch, band-of-128-rows).
// ---------------------------------------------------------------------------
__global__ __launch_bounds__(64) void dtw_sys8(const float* __restrict__ skew,
                                               unsigned long long* __restrict__ bndmsg,
                                               float* __restrict__ out) {
    __shared__ float pubring[128];
    __shared__ float dumpL[192];
    __shared__ float bndbuf[64];
    const int bid = blockIdx.x;
    const int b = bid & 15;            // batch; XCD = bid%8 = b%8 for all p
    const int p = bid >> 4;            // band 0..7
    const int l = threadIdx.x;

    const float4* B4 = (const float4*)skew + (size_t)b * 2 * PROWS * 16 + l;
    unsigned long long* BndOut = bndmsg + ((size_t)b * NPAIR + p) * TT;
    unsigned long long* BndIn  = bndmsg + ((size_t)b * NPAIR + (p > 0 ? p - 1 : 0)) * TT;

    bndbuf[l] = BIGV;                  // stays BIG for p==0 / drain

    float curA = BIGV, curB = BIGV;
    float diagA = (p == 0 && l == 0) ? 0.0f : BIGV;

    float qA[64], qB[64];              // [0..31]=plane0, [32..63]=plane1
    auto loadg = [&](int G, float (&q)[64]) {   // 32 steps, both planes
        const int t0 = (p * 1024 + 32 * G) & (PROWS - 1);   // 32-aligned wrap
        const float4* g0 = B4 + (size_t)(t0 >> 2) * 64;
        const float4* g1 = g0 + (size_t)PROWS * 16;         // plane 1
#pragma unroll
        for (int qd = 0; qd < 8; ++qd) {
            float4 v = g0[qd * 64];
            q[4 * qd + 0] = v.x; q[4 * qd + 1] = v.y;
            q[4 * qd + 2] = v.z; q[4 * qd + 3] = v.w;
        }
#pragma unroll
        for (int qd = 0; qd < 8; ++qd) {
            float4 v = g1[qd * 64];
            q[32 + 4 * qd + 0] = v.x; q[32 + 4 * qd + 1] = v.y;
            q[32 + 4 * qd + 2] = v.z; q[32 + 4 * qd + 3] = v.w;
        }
    };
    loadg(0, qA);
    loadg(1, qB);

    unsigned long long mcur = 0, mnext = 0;
    if (p > 0)
        mcur = __hip_atomic_load(&BndIn[l], __ATOMIC_RELAXED,
                                 __HIP_MEMORY_SCOPE_AGENT);

#pragma unroll 1
    for (int V = 0; V < 17; ++V) {
        // wait for boundary window V (tag V+1), via prefetched mcur
        if (p > 0 && V <= 15) {
            const unsigned want = (unsigned)(V + 1);
            while (!__all((int)((unsigned)(mcur >> 32) == want))) {
                __builtin_amdgcn_s_sleep(1);
                mcur = __hip_atomic_load(&BndIn[(size_t)64 * V + l],
                                         __ATOMIC_RELAXED,
                                         __HIP_MEMORY_SCOPE_AGENT);
            }
            bndbuf[l] = __uint_as_float((unsigned)mcur);
        }
        const bool is_pub = (l == 63) && (p < NB - 1);
        float* pA = (is_pub && V > 0) ? (pubring + (((V + 1) & 1) << 6))
                                      : (dumpL + l);
        float* pB = (is_pub && V < 16) ? (pubring + ((V & 1) << 6))
                                       : (dumpL + l);
        // two 32-step groups; refill used buffer right after consumption
        if (V == 0) {
            grp32<0, 0>(curA, curB, diagA, qA, bndbuf, pA, pB, l);
            loadg(2, qA);
            grp32<0, 32>(curA, curB, diagA, qB, bndbuf, pA, pB, l);
            loadg(3, qB);
        } else if (V < 16) {
            grp32<1, 0>(curA, curB, diagA, qA, bndbuf, pA, pB, l);
            loadg(2 * V + 2, qA);
            grp32<1, 32>(curA, curB, diagA, qB, bndbuf, pA, pB, l);
            if (V < 15) loadg(2 * V + 3, qB);
            else        loadg(33, qB);
        } else {
            grp32<2, 0>(curA, curB, diagA, qA, bndbuf, pA, pB, l);
            grp32<3, 32>(curA, curB, diagA, qB, bndbuf, pA, pB, l);
        }
        // late prefetch of next window's messages
        if (p > 0 && V < 15)
            mnext = __hip_atomic_load(&BndIn[(size_t)64 * (V + 1) + l],
                                      __ATOMIC_RELAXED,
                                      __HIP_MEMORY_SCOPE_AGENT);
        // flush boundary window V-1 (completed during window V)
        if (V >= 1 && p < NPAIR) {
            float fv = pubring[(((V + 1) & 1) << 6) + l];
            unsigned long long msg =
                ((unsigned long long)(unsigned)V << 32) | __float_as_uint(fv);
            __hip_atomic_store(&BndOut[(size_t)64 * (V - 1) + l], msg,
                               __ATOMIC_RELAXED, __HIP_MEMORY_SCOPE_AGENT);
        }
        mcur = mnext;
    }

    // band 7, lane 63: curB = R[1024][1024]
    if (p == NB - 1 && l == 63) atomicAdd(out, curB);
}

// ---------------------------------------------------------------------------
// Fallback (ws too small; not expected): naive fused DP.
// ---------------------------------------------------------------------------
__device__ __forceinline__ float softmin3(float a, float b, float c) {
    float m = fminf(fminf(a, b), c);
    float s = expf((m - a) * 100.0f) + expf((m - b) * 100.0f) + expf((m - c) * 100.0f);
    return m - 0.01f * logf(s);
}

__global__ __launch_bounds__(1024) void dtw_fly_kernel(const float* __restrict__ x,
                                                       const float* __restrict__ y,
                                                       float* __restrict__ out) {
    __shared__ float rbuf[3][TT + 1];
    const int b = blockIdx.x;
    const int t = threadIdx.x;

    float4 xr[16];
    const float4* xrow = (const float4*)(x + ((size_t)b * TT + t) * CC);
#pragma unroll
    for (int q = 0; q < 16; ++q) xr[q] = xrow[q];

    rbuf[0][t] = (t == 0) ? 0.0f : BIGV;
    rbuf[1][t] = BIGV;
    if (t == 0) { rbuf[0][TT] = BIGV; rbuf[1][TT] = BIGV; }
    __syncthreads();

    int p2 = 0, p1 = 1, pc = 2;
    float val = BIGV;
    for (int d = 2; d <= 2 * TT; ++d) {
        int j = d - t - 1;
        bool valid = (j >= 1) && (j <= TT);
        float cv = 0.0f;
        if (valid) {
            const float4* yr = (const float4*)(y + ((size_t)b * TT + (j - 1)) * CC);
#pragma unroll
            for (int q = 0; q < 16; ++q) {
                float4 yv = yr[q];
                float d0 = xr[q].x - yv.x, d1 = xr[q].y - yv.y;
                float d2 = xr[q].z - yv.z, d3 = xr[q].w - yv.w;
                cv += d0 * d0 + d1 * d1 + d2 * d2 + d3 * d3;
            }
        }
        float v = cv + softmin3(rbuf[p1][t], rbuf[p1][t + 1], rbuf[p2][t]);
        val = valid ? v : BIGV;
        rbuf[pc][t + 1] = val;
        if (t == 0) rbuf[pc][0] = BIGV;
        __syncthreads();
        int tmp = p2; p2 = p1; p1 = pc; pc = tmp;
    }
    if (t == TT - 1) atomicAdd(out, val);
}

extern "C" void kernel_launch(void* const* d_in, const int* in_sizes, int n_in,
                              void* d_out, int out_size, void* d_ws, size_t ws_size,
                              hipStream_t stream) {
    const float* x = (const float*)d_in[0];
    const float* y = (const float*)d_in[1];
    float* out = (float*)d_out;

    hipMemsetAsync(d_out, 0, sizeof(float) * out_size, stream);

    const size_t skew_b = (size_t)BB * 2 * PROWS * 64 * sizeof(float);       // 64 MiB
    const size_t msg_b  = (size_t)BB * NPAIR * TT * sizeof(unsigned long long); // 896 KiB

    if (ws_size >= skew_b + msg_b) {
        float* skew = (float*)d_ws;
        unsigned long long* bndmsg = (unsigned long long*)((char*)d_ws + skew_b);
        hipMemsetAsync(bndmsg, 0, msg_b, stream);   // tags := 0 (invalid)
        dim3 g1(16, 16, BB);
        skew_cost_kernel<<<g1, 256, 0, stream>>>(x, y, skew);
        dtw_sys8<<<128, 64, 0, stream>>>(skew, bndmsg, out);
    } else {
        dtw_fly_kernel<<<BB, 1024, 0, stream>>>(x, y, out);
    }
}